// Round 1
// baseline (709.768 us; speedup 1.0000x reference)
//
#include <hip/hip_runtime.h>
#include <hip/hip_bf16.h>

#define B_  256
#define N_  32768
#define D_  1024
#define H_  16
#define DH_ 64
#define NSPLIT 8

typedef __attribute__((ext_vector_type(8))) short bf16x8;
typedef __attribute__((ext_vector_type(4))) float f32x4;

static __device__ __forceinline__ short f2bf(float f) {
    union { __hip_bfloat16 h; short s; } u;
    u.h = __float2bfloat16(f);
    return u.s;
}

// ---------------------------------------------------------------------------
// C[M, Dout] (bf16) = alpha * A[M,K] @ W[Dout,K]^T   (A, W are f32 row-major)
// 128x128 tile, BK=32, 4 waves of 4x4 16x16x32 bf16 MFMA frags.
// block_n = blockIdx.x (fast) so consecutive blocks share the A row-panel (L2).
// ---------------------------------------------------------------------------
__global__ __launch_bounds__(256, 2)
void proj_gemm(const float* __restrict__ A, const float* __restrict__ W,
               short* __restrict__ C, int M, int K, int Dout, float alpha)
{
    __shared__ short As[128 * 40];   // rows padded to 40 bf16 (80 B, 16B-aligned)
    __shared__ short Ws[128 * 40];

    const int tid  = threadIdx.x;
    const int wave = tid >> 6;
    const int lane = tid & 63;
    const int quad = lane >> 4;
    const int l16  = lane & 15;

    const int block_n = blockIdx.x * 128;
    const int block_m = blockIdx.y * 128;
    const int wm = (wave & 1) * 64;
    const int wn = (wave >> 1) * 64;

    f32x4 acc[4][4];
#pragma unroll
    for (int i = 0; i < 4; ++i)
#pragma unroll
        for (int j = 0; j < 4; ++j) acc[i][j] = (f32x4){0.f, 0.f, 0.f, 0.f};

    for (int kt = 0; kt < K; kt += 32) {
        __syncthreads();
#pragma unroll
        for (int it = 0; it < 4; ++it) {
            int s  = it * 256 + tid;         // 0..1023
            int r  = s >> 3;                 // row 0..127
            int c4 = s & 7;                  // float4 index in 32-wide row
            float4 va = *(const float4*)(A + (size_t)(block_m + r) * K + kt + c4 * 4);
            float4 vw = *(const float4*)(W + (size_t)(block_n + r) * K + kt + c4 * 4);
            short4 ha = make_short4(f2bf(va.x), f2bf(va.y), f2bf(va.z), f2bf(va.w));
            short4 hw = make_short4(f2bf(vw.x), f2bf(vw.y), f2bf(vw.z), f2bf(vw.w));
            *(short4*)&As[r * 40 + c4 * 4] = ha;
            *(short4*)&Ws[r * 40 + c4 * 4] = hw;
        }
        __syncthreads();

        bf16x8 afrag[4], bfrag[4];
#pragma unroll
        for (int mi = 0; mi < 4; ++mi)
            afrag[mi] = *(const bf16x8*)&As[(wm + mi * 16 + l16) * 40 + quad * 8];
#pragma unroll
        for (int ni = 0; ni < 4; ++ni)
            bfrag[ni] = *(const bf16x8*)&Ws[(wn + ni * 16 + l16) * 40 + quad * 8];
#pragma unroll
        for (int mi = 0; mi < 4; ++mi)
#pragma unroll
            for (int ni = 0; ni < 4; ++ni)
                acc[mi][ni] = __builtin_amdgcn_mfma_f32_16x16x32_bf16(
                    afrag[mi], bfrag[ni], acc[mi][ni], 0, 0, 0);
    }

    // C/D layout: col = lane&15, row = quad*4 + reg  [m89-verified]
#pragma unroll
    for (int mi = 0; mi < 4; ++mi)
#pragma unroll
        for (int ni = 0; ni < 4; ++ni)
#pragma unroll
            for (int reg = 0; reg < 4; ++reg) {
                int r = block_m + wm + mi * 16 + quad * 4 + reg;
                int c = block_n + wn + ni * 16 + l16;
                C[(size_t)r * Dout + c] = f2bf(acc[mi][ni][reg] * alpha);
            }
}

// ---------------------------------------------------------------------------
// Flash attention: grid (NSPLIT, 4 qtiles, 16 heads), 256 thr (4 waves).
// Each wave owns 16 q-rows; waves share LDS-staged 64-key K/V chunks.
// qh [B][D] bf16 (pre-scaled by 1/8), kh [N][D] bf16, vhT [D][N] bf16.
// ---------------------------------------------------------------------------
__global__ __launch_bounds__(256, 2)
void attn_kernel(const short* __restrict__ qh, const short* __restrict__ kh,
                 const short* __restrict__ vhT, float* __restrict__ partO,
                 float* __restrict__ partM, float* __restrict__ partL)
{
    const int ns = blockIdx.x, qt = blockIdx.y, h = blockIdx.z;
    const int tid  = threadIdx.x;
    const int wave = tid >> 6;
    const int lane = tid & 63;
    const int quad = lane >> 4;
    const int l16  = lane & 15;

    __shared__ short Ks[64][72];      // [key][d]   (B-frag for QK^T: contiguous in d)
    __shared__ short Vt[64][72];      // [d][key]   (B-frag for PV: contiguous in key)
    __shared__ short Ps[4][16][72];   // per-wave P round-trip (C-layout -> A-layout)

    const int qrow = qt * 64 + wave * 16 + l16;
    bf16x8 aQ[2];
    aQ[0] = *(const bf16x8*)(qh + (size_t)qrow * D_ + h * DH_ + quad * 8);
    aQ[1] = *(const bf16x8*)(qh + (size_t)qrow * D_ + h * DH_ + 32 + quad * 8);

    f32x4 ofrag[4];
#pragma unroll
    for (int dt = 0; dt < 4; ++dt) ofrag[dt] = (f32x4){0.f, 0.f, 0.f, 0.f};
    float m_i[4], l_i[4];
#pragma unroll
    for (int r = 0; r < 4; ++r) { m_i[r] = -__builtin_inff(); l_i[r] = 0.f; }

    const int nPer = N_ / NSPLIT;   // 4096
    const int n0 = ns * nPer;

    for (int ch = 0; ch < nPer; ch += 64) {
        const int nb = n0 + ch;
        __syncthreads();
#pragma unroll
        for (int it = 0; it < 2; ++it) {
            int s  = it * 256 + tid;
            int r  = s >> 3;          // 0..63
            int c8 = s & 7;           // 8-element (16B) segment
            *(bf16x8*)&Ks[r][c8 * 8] =
                *(const bf16x8*)(kh + (size_t)(nb + r) * D_ + h * DH_ + c8 * 8);
            *(bf16x8*)&Vt[r][c8 * 8] =
                *(const bf16x8*)(vhT + (size_t)(h * DH_ + r) * N_ + nb + c8 * 8);
        }
        __syncthreads();

        // S[16 q][64 key] = Q @ K^T   (scale already folded into qh)
        f32x4 sfrag[4];
#pragma unroll
        for (int nt = 0; nt < 4; ++nt) sfrag[nt] = (f32x4){0.f, 0.f, 0.f, 0.f};
#pragma unroll
        for (int ks = 0; ks < 2; ++ks)
#pragma unroll
            for (int nt = 0; nt < 4; ++nt) {
                bf16x8 bK = *(const bf16x8*)&Ks[nt * 16 + l16][ks * 32 + quad * 8];
                sfrag[nt] = __builtin_amdgcn_mfma_f32_16x16x32_bf16(
                    aQ[ks], bK, sfrag[nt], 0, 0, 0);
            }

        // online softmax; lane holds rows quad*4+reg, key col l16 (+16*nt)
        float cmax[4];
#pragma unroll
        for (int r = 0; r < 4; ++r)
            cmax[r] = fmaxf(fmaxf(sfrag[0][r], sfrag[1][r]),
                            fmaxf(sfrag[2][r], sfrag[3][r]));
#pragma unroll
        for (int off = 1; off < 16; off <<= 1)
#pragma unroll
            for (int r = 0; r < 4; ++r)
                cmax[r] = fmaxf(cmax[r], __shfl_xor(cmax[r], off));

        float alpha[4], psum[4];
#pragma unroll
        for (int r = 0; r < 4; ++r) {
            float mn = fmaxf(m_i[r], cmax[r]);
            alpha[r] = __expf(m_i[r] - mn);
            m_i[r] = mn;
            psum[r] = 0.f;
        }
#pragma unroll
        for (int nt = 0; nt < 4; ++nt)
#pragma unroll
            for (int r = 0; r < 4; ++r) {
                float p = __expf(sfrag[nt][r] - m_i[r]);
                psum[r] += p;
                Ps[wave][quad * 4 + r][nt * 16 + l16] = f2bf(p);
            }
#pragma unroll
        for (int off = 1; off < 16; off <<= 1)
#pragma unroll
            for (int r = 0; r < 4; ++r) psum[r] += __shfl_xor(psum[r], off);
#pragma unroll
        for (int r = 0; r < 4; ++r) l_i[r] = l_i[r] * alpha[r] + psum[r];
#pragma unroll
        for (int dt = 0; dt < 4; ++dt)
#pragma unroll
            for (int r = 0; r < 4; ++r) ofrag[dt][r] *= alpha[r];

        // O += P @ V  (P via LDS round-trip into A-layout; within-wave, no barrier)
#pragma unroll
        for (int ks = 0; ks < 2; ++ks) {
            bf16x8 aP = *(const bf16x8*)&Ps[wave][l16][ks * 32 + quad * 8];
#pragma unroll
            for (int dt = 0; dt < 4; ++dt) {
                bf16x8 bV = *(const bf16x8*)&Vt[dt * 16 + l16][ks * 32 + quad * 8];
                ofrag[dt] = __builtin_amdgcn_mfma_f32_16x16x32_bf16(
                    aP, bV, ofrag[dt], 0, 0, 0);
            }
        }
    }

    const int bid = (h * 4 + qt) * NSPLIT + ns;
    float* Ob = partO + (size_t)bid * 4096;
#pragma unroll
    for (int dt = 0; dt < 4; ++dt)
#pragma unroll
        for (int r = 0; r < 4; ++r)
            Ob[(wave * 16 + quad * 4 + r) * 64 + dt * 16 + l16] = ofrag[dt][r];
    if (l16 == 0) {
#pragma unroll
        for (int r = 0; r < 4; ++r) {
            partM[bid * 64 + wave * 16 + quad * 4 + r] = m_i[r];
            partL[bid * 64 + wave * 16 + quad * 4 + r] = l_i[r];
        }
    }
}

// ---------------------------------------------------------------------------
// Merge NSPLIT partials per (head, qtile) row.
// ---------------------------------------------------------------------------
__global__ __launch_bounds__(256)
void merge_kernel(const float* __restrict__ partO, const float* __restrict__ partM,
                  const float* __restrict__ partL, float* __restrict__ out)
{
    int idx = blockIdx.x * 256 + threadIdx.x;    // 0 .. B*D-1
    int b   = idx >> 10;
    int col = idx & 1023;
    int h   = col >> 6;
    int d   = col & 63;
    int qt  = b >> 6;
    int rin = b & 63;
    int base = (h * 4 + qt) * NSPLIT;

    float mmax = -__builtin_inff();
#pragma unroll
    for (int s = 0; s < NSPLIT; ++s)
        mmax = fmaxf(mmax, partM[(base + s) * 64 + rin]);
    float L = 0.f, o = 0.f;
#pragma unroll
    for (int s = 0; s < NSPLIT; ++s) {
        float c = __expf(partM[(base + s) * 64 + rin] - mmax);
        L += c * partL[(base + s) * 64 + rin];
        o += c * partO[(size_t)(base + s) * 4096 + rin * 64 + d];
    }
    out[idx] = o / L;
}

// ---------------------------------------------------------------------------
extern "C" void kernel_launch(void* const* d_in, const int* in_sizes, int n_in,
                              void* d_out, int out_size, void* d_ws, size_t ws_size,
                              hipStream_t stream) {
    const float* q   = (const float*)d_in[0];
    const float* k   = (const float*)d_in[1];
    const float* v   = (const float*)d_in[2];
    const float* W_q = (const float*)d_in[3];
    const float* W_k = (const float*)d_in[4];
    const float* W_v = (const float*)d_in[5];
    float* out = (float*)d_out;

    // workspace layout (bf16 = short)
    short* qh  = (short*)d_ws;                  // 256*1024
    short* kh  = qh + (size_t)B_ * D_;          // 32768*1024
    short* vhT = kh + (size_t)N_ * D_;          // 1024*32768 (transposed V proj)
    float* partO = (float*)(vhT + (size_t)D_ * N_);       // 512 * 64*64
    float* partM = partO + (size_t)512 * 4096;            // 512 * 64
    float* partL = partM + (size_t)512 * 64;              // 512 * 64

    dim3 blk(256);
    const float inv_sqrt_dh = 0.125f;   // 1/sqrt(64), folded into qh

    // qh = (q @ W_q^T) * 1/8     : M=256,  Dout=1024  -> grid (8, 2)
    proj_gemm<<<dim3(8, 2), blk, 0, stream>>>(q, W_q, qh, B_, D_, D_, inv_sqrt_dh);
    // kh = k @ W_k^T             : M=32768, Dout=1024 -> grid (8, 256)
    proj_gemm<<<dim3(8, 256), blk, 0, stream>>>(k, W_k, kh, N_, D_, D_, 1.0f);
    // vhT = W_v @ v^T            : M=1024, Dout=32768 -> grid (256, 8)
    proj_gemm<<<dim3(256, 8), blk, 0, stream>>>(W_v, v, vhT, D_, D_, N_, 1.0f);

    attn_kernel<<<dim3(NSPLIT, 4, 16), blk, 0, stream>>>(qh, kh, vhT,
                                                         partO, partM, partL);
    merge_kernel<<<dim3((B_ * D_) / 256), blk, 0, stream>>>(partO, partM, partL, out);
}

// Round 2
// 650.953 us; speedup vs baseline: 1.0904x; 1.0904x over previous
//
#include <hip/hip_runtime.h>
#include <hip/hip_bf16.h>

#define B_  256
#define N_  32768
#define D_  1024
#define H_  16
#define DH_ 64
#define KSPLIT 16
#define STRIPE (N_ / KSPLIT)   // 2048 keys per split

typedef __attribute__((ext_vector_type(8))) short bf16x8;
typedef __attribute__((ext_vector_type(4))) float f32x4;

static __device__ __forceinline__ short f2bf(float f) {
    union { __hip_bfloat16 h; short s; } u;
    u.h = __float2bfloat16(f);
    return u.s;
}

// ---------------------------------------------------------------------------
// f32 -> bf16 convert (for the three weight matrices)
// ---------------------------------------------------------------------------
__global__ __launch_bounds__(256)
void f2b_kernel(const float* __restrict__ in, short* __restrict__ out, int n4)
{
    int i = blockIdx.x * 256 + threadIdx.x;
    if (i < n4) {
        float4 v = ((const float4*)in)[i];
        ((short4*)out)[i] = make_short4(f2bf(v.x), f2bf(v.y), f2bf(v.z), f2bf(v.w));
    }
}

// ---------------------------------------------------------------------------
// Hybrid GEMM: C = alpha * P[MP,K] x Qb[MQ,K]^T  (contraction over K rows)
//   P  : f32, staged to LDS with inline bf16 convert
//   Qb : bf16 (pre-converted weights), staged as-is
// SWAP=false: C[p][q] (row = P index),  ldc = MQ-stride given by caller
// SWAP=true : C[q][p] (row = Qb index) -- used for the transposed V proj
// 128x128 tile, BK=32, 4 waves x (4x4) 16x16x32 bf16 MFMA.
// Block mapping: per-XCD contiguous p-stripes, q-fast, so each XCD keeps its
// W panel + A panels in its own (non-coherent) L2.  [fix for 529MB over-fetch]
// ---------------------------------------------------------------------------
template<bool SWAP>
__global__ __launch_bounds__(256, 2)
void gemm_hybrid(const float* __restrict__ P, const short* __restrict__ Qb,
                 short* __restrict__ C, int MP, int MQ, int K, int ldc, float alpha)
{
    __shared__ __align__(16) short Pf[128 * 32];
    __shared__ __align__(16) short Qs[128 * 32];

    const int tid  = threadIdx.x;
    const int wave = tid >> 6;
    const int lane = tid & 63;
    const int quad = lane >> 4;
    const int l16  = lane & 15;

    const int gp = MP >> 7, gq = MQ >> 7;
    const int bid = blockIdx.x;
    int bp, bq;
    if (gp >= 8) {                       // XCD swizzle (HW: consecutive bid -> round-robin XCD)
        int xcd = bid & 7, w = bid >> 3, sp = gp >> 3;
        bp = xcd * sp + w / gq;
        bq = w % gq;
    } else { bp = bid / gq; bq = bid % gq; }

    const int wm = (wave & 1) * 64;
    const int wn = (wave >> 1) * 64;

    f32x4 acc[4][4];
#pragma unroll
    for (int i = 0; i < 4; ++i)
#pragma unroll
        for (int j = 0; j < 4; ++j) acc[i][j] = (f32x4){0.f, 0.f, 0.f, 0.f};

    for (int kt = 0; kt < K; kt += 32) {
        __syncthreads();
        // stage P tile (f32 -> bf16), 128x32
#pragma unroll
        for (int it = 0; it < 4; ++it) {
            int s = it * 256 + tid, r = s >> 3, c4 = s & 7;
            float4 v = *(const float4*)(P + (size_t)(bp * 128 + r) * K + kt + c4 * 4);
            *(short4*)&Pf[r * 32 + c4 * 4] =
                make_short4(f2bf(v.x), f2bf(v.y), f2bf(v.z), f2bf(v.w));
        }
        // stage Qb tile (bf16 passthrough), 128x32
#pragma unroll
        for (int it = 0; it < 2; ++it) {
            int s = it * 256 + tid, r = s >> 2, c8 = s & 3;
            *(bf16x8*)&Qs[r * 32 + c8 * 8] =
                *(const bf16x8*)(Qb + (size_t)(bq * 128 + r) * K + kt + c8 * 8);
        }
        __syncthreads();

        const short* LA = SWAP ? Qs : Pf;   // MFMA A-operand side
        const short* LB = SWAP ? Pf : Qs;   // MFMA B-operand side
        bf16x8 af[4], bf[4];
#pragma unroll
        for (int mi = 0; mi < 4; ++mi)
            af[mi] = *(const bf16x8*)&LA[(wm + mi * 16 + l16) * 32 + quad * 8];
#pragma unroll
        for (int ni = 0; ni < 4; ++ni)
            bf[ni] = *(const bf16x8*)&LB[(wn + ni * 16 + l16) * 32 + quad * 8];
#pragma unroll
        for (int mi = 0; mi < 4; ++mi)
#pragma unroll
            for (int ni = 0; ni < 4; ++ni)
                acc[mi][ni] = __builtin_amdgcn_mfma_f32_16x16x32_bf16(
                    af[mi], bf[ni], acc[mi][ni], 0, 0, 0);
    }

    // C/D layout: col = lane&15, row = quad*4 + reg  [m89-verified]
    const int rb = (SWAP ? bq : bp) * 128;
    const int cb = (SWAP ? bp : bq) * 128;
#pragma unroll
    for (int mi = 0; mi < 4; ++mi)
#pragma unroll
        for (int ni = 0; ni < 4; ++ni)
#pragma unroll
            for (int reg = 0; reg < 4; ++reg) {
                int r = rb + wm + mi * 16 + quad * 4 + reg;
                int c = cb + wn + ni * 16 + l16;
                C[(size_t)r * ldc + c] = f2bf(acc[mi][ni][reg] * alpha);
            }
}

// ---------------------------------------------------------------------------
// Flash attention, transposed-score form.  Grid (KSPLIT, 2, 16 heads),
// 256 thr = 4 independent waves (no __syncthreads in the loop).
// Each wave: 32 q-rows (2 j-frags), streams its 2048-key stripe in 64-key
// chunks, K/V fragments loaded directly global->VGPR.
//   S^T = K·Q^T  : D[i=key][j=qrow]  -> per-lane keys quad*4+reg, qrow=l16
//   O^T = V·P    : D[i=d  ][j=qrow]
// P goes C-layout -> B-layout via per-wave LDS (8x ds_write_b64 + 4x b128).
// ---------------------------------------------------------------------------
__global__ __launch_bounds__(256, 2)
void attn_kernel(const short* __restrict__ qh, const short* __restrict__ kh,
                 const short* __restrict__ vhT, float* __restrict__ partO,
                 float* __restrict__ partM, float* __restrict__ partL)
{
    const int st = blockIdx.x, qb2 = blockIdx.y, h = blockIdx.z;
    const int tid  = threadIdx.x;
    const int wave = tid >> 6;
    const int lane = tid & 63;
    const int quad = lane >> 4;
    const int l16  = lane & 15;

    __shared__ __align__(16) short Ps[4][32][72];   // per-wave P round-trip (pad 72)

    const int qbase = qb2 * 128 + wave * 32;
    const int hoff  = h * DH_;

    // Q fragments (register-resident, pre-scaled by 1/8 in qh)
    bf16x8 qfr[2][2];
#pragma unroll
    for (int qf = 0; qf < 2; ++qf)
#pragma unroll
        for (int ks = 0; ks < 2; ++ks)
            qfr[qf][ks] = *(const bf16x8*)(qh + (size_t)(qbase + qf * 16 + l16) * D_
                                           + hoff + ks * 32 + quad * 8);

    f32x4 ofrag[2][4];
#pragma unroll
    for (int qf = 0; qf < 2; ++qf)
#pragma unroll
        for (int dt = 0; dt < 4; ++dt) ofrag[qf][dt] = (f32x4){0.f, 0.f, 0.f, 0.f};
    float m_i[2] = {-__builtin_inff(), -__builtin_inff()};
    float l_i[2] = {0.f, 0.f};

    const int n0 = st * STRIPE;

    // prologue: K frags for chunk 0
    bf16x8 akf[4][2];
#pragma unroll
    for (int kf = 0; kf < 4; ++kf)
#pragma unroll
        for (int ks = 0; ks < 2; ++ks)
            akf[kf][ks] = *(const bf16x8*)(kh + (size_t)(n0 + kf * 16 + l16) * D_
                                           + hoff + ks * 32 + quad * 8);

    for (int ch = 0; ch < STRIPE; ch += 64) {
        const int nb = n0 + ch;

        // ---- S^T = K·Q^T
        f32x4 sf[4][2];
#pragma unroll
        for (int kf = 0; kf < 4; ++kf)
#pragma unroll
            for (int qf = 0; qf < 2; ++qf) sf[kf][qf] = (f32x4){0.f, 0.f, 0.f, 0.f};
#pragma unroll
        for (int ks = 0; ks < 2; ++ks)
#pragma unroll
            for (int kf = 0; kf < 4; ++kf)
#pragma unroll
                for (int qf = 0; qf < 2; ++qf)
                    sf[kf][qf] = __builtin_amdgcn_mfma_f32_16x16x32_bf16(
                        akf[kf][ks], qfr[qf][ks], sf[kf][qf], 0, 0, 0);

        // ---- issue V loads for this chunk (latency hidden by softmax)
        bf16x8 avf[4][2];
#pragma unroll
        for (int dt = 0; dt < 4; ++dt)
#pragma unroll
            for (int g = 0; g < 2; ++g)
                avf[dt][g] = *(const bf16x8*)(vhT + (size_t)(hoff + dt * 16 + l16) * N_
                                              + nb + g * 32 + quad * 8);

        // ---- prefetch K frags for next chunk (registers free after QK MFMAs)
        const int nbn = (ch + 64 < STRIPE) ? nb + 64 : nb;
#pragma unroll
        for (int kf = 0; kf < 4; ++kf)
#pragma unroll
            for (int ks = 0; ks < 2; ++ks)
                akf[kf][ks] = *(const bf16x8*)(kh + (size_t)(nbn + kf * 16 + l16) * D_
                                               + hoff + ks * 32 + quad * 8);

        // ---- online softmax (per qf: 16 scores/lane, keys = 16kf+quad*4+reg)
#pragma unroll
        for (int qf = 0; qf < 2; ++qf) {
            float mx = sf[0][qf][0];
#pragma unroll
            for (int kf = 0; kf < 4; ++kf)
#pragma unroll
                for (int r = 0; r < 4; ++r) mx = fmaxf(mx, sf[kf][qf][r]);
            mx = fmaxf(mx, __shfl_xor(mx, 16));
            mx = fmaxf(mx, __shfl_xor(mx, 32));
            float mn = fmaxf(m_i[qf], mx);
            float al = __expf(m_i[qf] - mn);
            m_i[qf] = mn;
            float ps = 0.f;
#pragma unroll
            for (int kf = 0; kf < 4; ++kf) {
                float p0 = __expf(sf[kf][qf][0] - mn);
                float p1 = __expf(sf[kf][qf][1] - mn);
                float p2 = __expf(sf[kf][qf][2] - mn);
                float p3 = __expf(sf[kf][qf][3] - mn);
                ps += (p0 + p1) + (p2 + p3);
                *(short4*)&Ps[wave][qf * 16 + l16][kf * 16 + quad * 4] =
                    make_short4(f2bf(p0), f2bf(p1), f2bf(p2), f2bf(p3));
            }
            ps += __shfl_xor(ps, 16);
            ps += __shfl_xor(ps, 32);
            l_i[qf] = l_i[qf] * al + ps;
#pragma unroll
            for (int dt = 0; dt < 4; ++dt) ofrag[qf][dt] *= al;
        }

        // ---- O^T += V·P  (per-wave LDS, compiler inserts lgkmcnt)
#pragma unroll
        for (int qf = 0; qf < 2; ++qf)
#pragma unroll
            for (int g = 0; g < 2; ++g) {
                bf16x8 bP = *(const bf16x8*)&Ps[wave][qf * 16 + l16][g * 32 + quad * 8];
#pragma unroll
                for (int dt = 0; dt < 4; ++dt)
                    ofrag[qf][dt] = __builtin_amdgcn_mfma_f32_16x16x32_bf16(
                        avf[dt][g], bP, ofrag[qf][dt], 0, 0, 0);
            }
    }

    // epilogue: O^T C-layout -> partO[pid][row 0..31][d 0..63]
    const int pid = ((h * KSPLIT + st) * 2 + qb2) * 4 + wave;
#pragma unroll
    for (int qf = 0; qf < 2; ++qf)
#pragma unroll
        for (int dt = 0; dt < 4; ++dt)
            *(f32x4*)&partO[((size_t)pid * 32 + qf * 16 + l16) * 64 + dt * 16 + quad * 4]
                = ofrag[qf][dt];
    if (quad == 0) {
#pragma unroll
        for (int qf = 0; qf < 2; ++qf) {
            partM[pid * 32 + qf * 16 + l16] = m_i[qf];
            partL[pid * 32 + qf * 16 + l16] = l_i[qf];
        }
    }
}

// ---------------------------------------------------------------------------
// Merge KSPLIT partials.
// ---------------------------------------------------------------------------
__global__ __launch_bounds__(256)
void merge_kernel(const float* __restrict__ partO, const float* __restrict__ partM,
                  const float* __restrict__ partL, float* __restrict__ out)
{
    int idx = blockIdx.x * 256 + threadIdx.x;   // 0 .. B*D-1
    int b   = idx >> 10;
    int col = idx & 1023;
    int h   = col >> 6;
    int d   = col & 63;
    int blk32 = b >> 5, rin = b & 31;
    int qb2 = blk32 >> 2, w = blk32 & 3;

    float mmax = -__builtin_inff();
#pragma unroll
    for (int st = 0; st < KSPLIT; ++st) {
        int pid = ((h * KSPLIT + st) * 2 + qb2) * 4 + w;
        mmax = fmaxf(mmax, partM[pid * 32 + rin]);
    }
    float L = 0.f, o = 0.f;
#pragma unroll
    for (int st = 0; st < KSPLIT; ++st) {
        int pid = ((h * KSPLIT + st) * 2 + qb2) * 4 + w;
        float c = __expf(partM[pid * 32 + rin] - mmax);
        L += c * partL[pid * 32 + rin];
        o += c * partO[((size_t)pid * 32 + rin) * 64 + d];
    }
    out[idx] = o / L;
}

// ---------------------------------------------------------------------------
extern "C" void kernel_launch(void* const* d_in, const int* in_sizes, int n_in,
                              void* d_out, int out_size, void* d_ws, size_t ws_size,
                              hipStream_t stream) {
    const float* q   = (const float*)d_in[0];
    const float* k   = (const float*)d_in[1];
    const float* v   = (const float*)d_in[2];
    const float* W_q = (const float*)d_in[3];
    const float* W_k = (const float*)d_in[4];
    const float* W_v = (const float*)d_in[5];
    float* out = (float*)d_out;

    // workspace layout (~152 MB)
    short* qh  = (short*)d_ws;                    // 256x1024      (0.5 MB)
    short* kh  = qh  + (size_t)B_ * D_;           // 32768x1024    (64 MB)
    short* vhT = kh  + (size_t)N_ * D_;           // 1024x32768    (64 MB)
    short* Wqb = vhT + (size_t)D_ * N_;           // 1024x1024 bf16 (2 MB)
    short* Wkb = Wqb + (size_t)D_ * D_;
    short* Wvb = Wkb + (size_t)D_ * D_;
    float* partO = (float*)(Wvb + (size_t)D_ * D_);   // 2048 x 32 x 64 (16 MB)
    float* partM = partO + (size_t)2048 * 32 * 64;
    float* partL = partM + (size_t)2048 * 32;

    dim3 blk(256);
    const int w4 = (D_ * D_) / 4;   // 262144 float4s per weight

    f2b_kernel<<<dim3(w4 / 256), blk, 0, stream>>>(W_q, Wqb, w4);
    f2b_kernel<<<dim3(w4 / 256), blk, 0, stream>>>(W_k, Wkb, w4);
    f2b_kernel<<<dim3(w4 / 256), blk, 0, stream>>>(W_v, Wvb, w4);

    // qh = (q @ W_q^T) * 1/8 : C[q-row][do], grid 2*8
    gemm_hybrid<false><<<dim3(2 * 8), blk, 0, stream>>>(q, Wqb, qh, B_, D_, D_, D_, 0.125f);
    // kh = k @ W_k^T         : C[key][do],  grid 256*8
    gemm_hybrid<false><<<dim3(256 * 8), blk, 0, stream>>>(k, Wkb, kh, N_, D_, D_, D_, 1.0f);
    // vhT = (v @ W_v^T)^T    : C[do][n],   grid 256*8  (row = W_v index)
    gemm_hybrid<true><<<dim3(256 * 8), blk, 0, stream>>>(v, Wvb, vhT, N_, D_, D_, N_, 1.0f);

    attn_kernel<<<dim3(KSPLIT, 2, H_), blk, 0, stream>>>(qh, kh, vhT, partO, partM, partL);
    merge_kernel<<<dim3((B_ * D_) / 256), blk, 0, stream>>>(partO, partM, partL, out);
}